// Round 2
// baseline (1170.849 us; speedup 1.0000x reference)
//
#include <hip/hip_runtime.h>
#include <hip/hip_bf16.h>

#define N_NODES 50000
#define N_EDGES 600000
#define DD 128
#define EPS 1e-6f

typedef __bf16 bf16;
typedef _Float16 f16;
typedef __attribute__((ext_vector_type(8))) __bf16 bf16x8;
typedef __attribute__((ext_vector_type(2))) _Float16 f16x2;
typedef __attribute__((ext_vector_type(4))) float f32x4;

__device__ __forceinline__ f32x4 mfma16(bf16x8 a, bf16x8 b, f32x4 c) {
    return __builtin_amdgcn_mfma_f32_16x16x32_bf16(a, b, c, 0, 0, 0);
}

// ---------------- W f32 -> bf16 conversion (5 matrices of 128x128) ----------------
__global__ void conv_w_kernel(const float* __restrict__ WA, const float* __restrict__ WB,
                              const float* __restrict__ WC, const float* __restrict__ WD,
                              const float* __restrict__ WE, bf16* __restrict__ out) {
    int i = blockIdx.x * 256 + threadIdx.x;   // 0 .. 81919
    const float* srcs[5] = {WA, WB, WC, WD, WE};
    int w = i >> 14;
    int j = i & 16383;
    out[i] = (bf16)srcs[w][j];
}

// ---------------- counting sort by dst: histogram -> scan -> scatter ---------------
__global__ void hist_kernel(const int* __restrict__ dst, int* __restrict__ count) {
    int i = blockIdx.x * 256 + threadIdx.x;
    if (i < N_EDGES) atomicAdd(&count[dst[i]], 1);
}

__global__ __launch_bounds__(1024) void scan_kernel(const int* __restrict__ count,
                                                    int* __restrict__ off,
                                                    int* __restrict__ cursor) {
    __shared__ int part[1024];
    const int CH = 49;                     // 1024*49 = 50176 >= 50000
    int t = threadIdx.x;
    int base = t * CH;
    int s = 0;
    for (int i = 0; i < CH; ++i) {
        int idx = base + i;
        if (idx < N_NODES) s += count[idx];
    }
    part[t] = s;
    __syncthreads();
    for (int ofs = 1; ofs < 1024; ofs <<= 1) {
        int v = (t >= ofs) ? part[t - ofs] : 0;
        __syncthreads();
        part[t] += v;
        __syncthreads();
    }
    int run = (t == 0) ? 0 : part[t - 1];
    for (int i = 0; i < CH; ++i) {
        int idx = base + i;
        if (idx < N_NODES) {
            off[idx] = run;
            cursor[idx] = run;
            run += count[idx];
        }
    }
    if (t == 1023) off[N_NODES] = part[1023];
}

__global__ void scatter_kernel(const int* __restrict__ dst, int* __restrict__ cursor,
                               int* __restrict__ edge_ids) {
    int i = blockIdx.x * 256 + threadIdx.x;
    if (i < N_EDGES) {
        int d = dst[i];
        int pos = atomicAdd(&cursor[d], 1);
        edge_ids[pos] = i;
    }
}

// ---------------- node GEMMs: Ah, DBh(interleaved D,B), Eh = h @ W.T + b -----------
__global__ __launch_bounds__(256) void node_gemm_kernel(
    const float* __restrict__ h, const bf16* __restrict__ Wb,
    const float* __restrict__ bA, const float* __restrict__ bB,
    const float* __restrict__ bD, const float* __restrict__ bE,
    bf16* __restrict__ Ah, bf16* __restrict__ DBh, bf16* __restrict__ Eh)
{
    __shared__ bf16 hs[64 * 136];   // stride 136 bf16: 2-way LDS aliasing only (free)
    int tid = threadIdx.x;
    int n0 = blockIdx.x * 64;

#pragma unroll
    for (int it = 0; it < 8; ++it) {
        int idx = it * 256 + tid;
        int row = idx >> 5;
        int c4  = idx & 31;
        int grow = n0 + row;
        if (grow >= N_NODES) grow = N_NODES - 1;
        float4 v = ((const float4*)h)[grow * 32 + c4];
        bf16* d = &hs[row * 136 + c4 * 4];
        d[0] = (bf16)v.x; d[1] = (bf16)v.y; d[2] = (bf16)v.z; d[3] = (bf16)v.w;
    }
    __syncthreads();

    int lane = tid & 63, wv = tid >> 6;
    int l15 = lane & 15, quad = lane >> 4;

    // order: A, B, D, E  (W offsets 0,1,3,4)
    const bf16* Wsel[4] = {Wb, Wb + 16384, Wb + 3 * 16384, Wb + 4 * 16384};
    const float* bsel[4] = {bA, bB, bD, bE};

#pragma unroll 1
    for (int wi = 0; wi < 4; ++wi) {
        const bf16* W = Wsel[wi];
        f32x4 acc[4][2] = {};
#pragma unroll
        for (int ks = 0; ks < 4; ++ks) {
            int kk = ks * 32 + quad * 8;
            bf16x8 b0 = *(const bf16x8*)&W[((2 * wv) * 16 + l15) * 128 + kk];
            bf16x8 b1 = *(const bf16x8*)&W[((2 * wv + 1) * 16 + l15) * 128 + kk];
#pragma unroll
            for (int mt = 0; mt < 4; ++mt) {
                bf16x8 a = *(const bf16x8*)&hs[(mt * 16 + l15) * 136 + kk];
                acc[mt][0] = mfma16(a, b0, acc[mt][0]);
                acc[mt][1] = mfma16(a, b1, acc[mt][1]);
            }
        }
#pragma unroll
        for (int nt = 0; nt < 2; ++nt) {
            int col = (2 * wv + nt) * 16 + l15;
            float bias = bsel[wi][col];
#pragma unroll
            for (int mt = 0; mt < 4; ++mt) {
#pragma unroll
                for (int r = 0; r < 4; ++r) {
                    int row = mt * 16 + quad * 4 + r;
                    int grow = n0 + row;
                    if (grow < N_NODES) {
                        bf16 v = (bf16)(acc[mt][nt][r] + bias);
                        if (wi == 0)      Ah[(size_t)grow * 128 + col] = v;
                        else if (wi == 1) DBh[(size_t)grow * 256 + col * 2 + 1] = v;  // Bh
                        else if (wi == 2) DBh[(size_t)grow * 256 + col * 2 + 0] = v;  // Dh
                        else              Eh[(size_t)grow * 128 + col] = v;
                    }
                }
            }
        }
    }
}

// ---------------- edge kernel: Ce GEMM + gather + gate + e_out + packed store ------
__global__ __launch_bounds__(256) void edge_kernel(
    const float* __restrict__ e, const int* __restrict__ src, const int* __restrict__ dst,
    const bf16* __restrict__ WCb, const float* __restrict__ bC,
    const bf16* __restrict__ DBh, const bf16* __restrict__ Eh,
    unsigned* __restrict__ edge_buf, float* __restrict__ e_out)
{
    __shared__ bf16 es[64 * 136];
    __shared__ int s_src[64];
    __shared__ int s_dst[64];
    int tid = threadIdx.x;
    int e0 = blockIdx.x * 64;

#pragma unroll
    for (int it = 0; it < 8; ++it) {
        int idx = it * 256 + tid;
        int row = idx >> 5;
        int c4  = idx & 31;
        float4 v = ((const float4*)e)[(size_t)(e0 + row) * 32 + c4];
        bf16* d = &es[row * 136 + c4 * 4];
        d[0] = (bf16)v.x; d[1] = (bf16)v.y; d[2] = (bf16)v.z; d[3] = (bf16)v.w;
    }
    if (tid < 64)       s_src[tid] = src[e0 + tid];
    else if (tid < 128) s_dst[tid - 64] = dst[e0 + tid - 64];
    __syncthreads();

    int lane = tid & 63, wv = tid >> 6;
    int l15 = lane & 15, quad = lane >> 4;

    f32x4 acc[4][2] = {};
#pragma unroll
    for (int ks = 0; ks < 4; ++ks) {
        int kk = ks * 32 + quad * 8;
        bf16x8 b0 = *(const bf16x8*)&WCb[((2 * wv) * 16 + l15) * 128 + kk];
        bf16x8 b1 = *(const bf16x8*)&WCb[((2 * wv + 1) * 16 + l15) * 128 + kk];
#pragma unroll
        for (int mt = 0; mt < 4; ++mt) {
            bf16x8 a = *(const bf16x8*)&es[(mt * 16 + l15) * 136 + kk];
            acc[mt][0] = mfma16(a, b0, acc[mt][0]);
            acc[mt][1] = mfma16(a, b1, acc[mt][1]);
        }
    }

#pragma unroll
    for (int nt = 0; nt < 2; ++nt) {
        int col = (2 * wv + nt) * 16 + l15;
        float bc = bC[col];
#pragma unroll
        for (int mt = 0; mt < 4; ++mt) {
#pragma unroll
            for (int r = 0; r < 4; ++r) {
                int row = mt * 16 + quad * 4 + r;
                int ei = e0 + row;
                int s  = s_src[row];
                int dd = s_dst[row];
                union { unsigned u; bf16 b[2]; } db;
                db.u = *(const unsigned*)&DBh[(size_t)s * 256 + col * 2];
                float dh = (float)db.b[0];
                float bh = (float)db.b[1];
                float eh = (float)Eh[(size_t)dd * 128 + col];
                float enew = acc[mt][nt][r] + bc + dh + eh;
                float sg = 1.0f / (1.0f + __expf(-enew));
                float ein = e[(size_t)ei * 128 + col];
                e_out[(size_t)ei * 128 + col] = ein + enew * sg;   // e + silu(e_new)
                union { unsigned u; f16x2 p; } pk;
                pk.p.x = (f16)sg;
                pk.p.y = (f16)(bh * sg);
                edge_buf[(size_t)ei * 128 + col] = pk.u;
            }
        }
    }
}

// ---------------- aggregate + finalize: one wave per node --------------------------
__global__ __launch_bounds__(256) void agg_final_kernel(
    const float* __restrict__ h, const bf16* __restrict__ Ah,
    const unsigned* __restrict__ edge_buf,
    const int* __restrict__ off, const int* __restrict__ edge_ids,
    float* __restrict__ h_out)
{
    int wid = (blockIdx.x * 256 + threadIdx.x) >> 6;   // node id
    int lane = threadIdx.x & 63;
    if (wid >= N_NODES) return;

    int beg = off[wid], end = off[wid + 1];
    float ss0 = 0.f, sm0 = 0.f, ss1 = 0.f, sm1 = 0.f;

    int k = beg;
    for (; k + 1 < end; k += 2) {
        int e0 = edge_ids[k];
        int e1 = edge_ids[k + 1];
        uint2 v0 = *(const uint2*)&edge_buf[(size_t)e0 * 128 + lane * 2];
        uint2 v1 = *(const uint2*)&edge_buf[(size_t)e1 * 128 + lane * 2];
        union { unsigned u; f16x2 p; } a, b, c, d;
        a.u = v0.x; b.u = v0.y; c.u = v1.x; d.u = v1.y;
        ss0 += (float)a.p.x + (float)c.p.x;
        sm0 += (float)a.p.y + (float)c.p.y;
        ss1 += (float)b.p.x + (float)d.p.x;
        sm1 += (float)b.p.y + (float)d.p.y;
    }
    if (k < end) {
        int e0 = edge_ids[k];
        uint2 v0 = *(const uint2*)&edge_buf[(size_t)e0 * 128 + lane * 2];
        union { unsigned u; f16x2 p; } a, b;
        a.u = v0.x; b.u = v0.y;
        ss0 += (float)a.p.x; sm0 += (float)a.p.y;
        ss1 += (float)b.p.x; sm1 += (float)b.p.y;
    }

    int c0 = lane * 2;
    union { unsigned u; bf16 b[2]; } A;
    A.u = *(const unsigned*)&Ah[(size_t)wid * 128 + c0];
    float hn0 = (float)A.b[0] + sm0 / (ss0 + EPS);
    float hn1 = (float)A.b[1] + sm1 / (ss1 + EPS);
    float2 hin = *(const float2*)&h[(size_t)wid * 128 + c0];
    float2 o;
    o.x = hin.x + hn0 * (1.0f / (1.0f + __expf(-hn0)));
    o.y = hin.y + hn1 * (1.0f / (1.0f + __expf(-hn1)));
    *(float2*)&h_out[(size_t)wid * 128 + c0] = o;
}

extern "C" void kernel_launch(void* const* d_in, const int* in_sizes, int n_in,
                              void* d_out, int out_size, void* d_ws, size_t ws_size,
                              hipStream_t stream) {
    const float* h   = (const float*)d_in[0];
    const float* e   = (const float*)d_in[1];
    const int*   src = (const int*)d_in[2];
    const int*   dst = (const int*)d_in[3];
    const float* WA = (const float*)d_in[4];  const float* bA = (const float*)d_in[5];
    const float* WB = (const float*)d_in[6];  const float* bB = (const float*)d_in[7];
    const float* WC = (const float*)d_in[8];  const float* bC = (const float*)d_in[9];
    const float* WD = (const float*)d_in[10]; const float* bD = (const float*)d_in[11];
    const float* WE = (const float*)d_in[12]; const float* bE = (const float*)d_in[13];

    float* h_out = (float*)d_out;
    float* e_out = h_out + (size_t)N_NODES * DD;

    char* ws = (char*)d_ws;
    bf16* Wb = (bf16*)ws;              ws += (size_t)5 * 16384 * sizeof(bf16);   // 160KB
    bf16* Ah = (bf16*)ws;              ws += (size_t)N_NODES * DD * sizeof(bf16);
    bf16* DBh = (bf16*)ws;             ws += (size_t)N_NODES * DD * 2 * sizeof(bf16);
    bf16* Eh = (bf16*)ws;              ws += (size_t)N_NODES * DD * sizeof(bf16);
    unsigned* edge_buf = (unsigned*)ws; ws += (size_t)N_EDGES * DD * sizeof(unsigned); // 307MB
    int* edge_ids = (int*)ws;          ws += (size_t)N_EDGES * sizeof(int);
    int* count = (int*)ws;             ws += (size_t)N_NODES * sizeof(int);
    int* off = (int*)ws;               ws += (size_t)(N_NODES + 4) * sizeof(int);
    int* cursor = (int*)ws;            ws += (size_t)N_NODES * sizeof(int);

    hipMemsetAsync(count, 0, (size_t)N_NODES * sizeof(int), stream);
    conv_w_kernel<<<320, 256, 0, stream>>>(WA, WB, WC, WD, WE, Wb);
    hist_kernel<<<(N_EDGES + 255) / 256, 256, 0, stream>>>(dst, count);
    scan_kernel<<<1, 1024, 0, stream>>>(count, off, cursor);
    scatter_kernel<<<(N_EDGES + 255) / 256, 256, 0, stream>>>(dst, cursor, edge_ids);
    node_gemm_kernel<<<(N_NODES + 63) / 64, 256, 0, stream>>>(
        h, Wb, bA, bB, bD, bE, Ah, DBh, Eh);
    edge_kernel<<<N_EDGES / 64, 256, 0, stream>>>(
        e, src, dst, Wb + 2 * 16384, bC, DBh, Eh, edge_buf, e_out);
    agg_final_kernel<<<(N_NODES * 64 + 255) / 256, 256, 0, stream>>>(
        h, Ah, edge_buf, off, edge_ids, h_out);
}